// Round 17
// baseline (1574.489 us; speedup 1.0000x reference)
//
#include <hip/hip_runtime.h>
#include <cstdint>
#include <cstddef>

#define S_LEN 2048
#define HID   4096
#define INTER 11008
#define NHEADS 32
#define HD    128

typedef __attribute__((ext_vector_type(4))) float  f32x4;
typedef __attribute__((ext_vector_type(8))) __bf16 bf16x8;
typedef __attribute__((ext_vector_type(8))) short  s16x8;
typedef __attribute__((ext_vector_type(4))) short  s16x4;

__device__ __forceinline__ float bf2f(short s) {
  unsigned u = ((unsigned)(unsigned short)s) << 16;
  return __builtin_bit_cast(float, u);
}
__device__ __forceinline__ short f2bf(float f) {
  unsigned u = __builtin_bit_cast(unsigned, f);
  u += 0x7FFFu + ((u >> 16) & 1u);
  return (short)(u >> 16);
}
__device__ __forceinline__ f32x4 mfma16(s16x8 a, s16x8 b, f32x4 c) {
  return __builtin_amdgcn_mfma_f32_16x16x32_bf16(
      __builtin_bit_cast(bf16x8, a), __builtin_bit_cast(bf16x8, b), c, 0, 0, 0);
}
__device__ __forceinline__ void gload_lds16(const void* g, void* l) {
  __builtin_amdgcn_global_load_lds(
      (const __attribute__((address_space(1))) void*)g,
      (__attribute__((address_space(3))) void*)l, 16, 0, 0);
}

// ---- merged: [0,nrows) rmsnorm rows; [nrows,..) Wq dequant tiles (64x64) ----
__global__ __launch_bounds__(256) void rmsdq_kernel(const float* __restrict__ x,
                                                    const float* __restrict__ w,
                                                    short* __restrict__ xout,
                                                    const int* __restrict__ qw,
                                                    const int* __restrict__ qz,
                                                    const float* __restrict__ sc,
                                                    short* __restrict__ wt,
                                                    int nrows) {
  __shared__ short tile[4608];
  __shared__ float psum[4];
  int bid = blockIdx.x;
  int tid = threadIdx.x;
  if (bid < nrows) {
    const float* xr = x + (size_t)bid * HID;
    short* orow = xout + (size_t)bid * HID;
    f32x4 v[4];
    float ss = 0.f;
#pragma unroll
    for (int i = 0; i < 4; ++i) {
      v[i] = ((const f32x4*)xr)[i * 256 + tid];
      ss += v[i][0] * v[i][0] + v[i][1] * v[i][1] + v[i][2] * v[i][2] + v[i][3] * v[i][3];
    }
#pragma unroll
    for (int off = 32; off > 0; off >>= 1) ss += __shfl_xor(ss, off);
    if ((tid & 63) == 0) psum[tid >> 6] = ss;
    __syncthreads();
    float tot = psum[0] + psum[1] + psum[2] + psum[3];
    float r = rsqrtf(tot * (1.0f / (float)HID) + 1e-6f);
#pragma unroll
    for (int i = 0; i < 4; ++i) {
      int base = (i * 256 + tid) * 4;
      s16x4 o;
#pragma unroll
      for (int j = 0; j < 4; ++j) o[j] = f2bf(v[i][j] * r * w[base + j]);
      *(s16x4*)&orow[base] = o;
    }
  } else {
    int id = bid - nrows;
    int n0 = (id & 63) * 64;
    int k0 = (id >> 6) * 64;
    int g = k0 >> 7;
    int qr0 = k0 >> 3;
#pragma unroll
    for (int i = 0; i < 2; ++i) {
      int idx = tid + i * 256;
      int r = idx >> 6;
      int n = idx & 63;
      int gc = n0 + n;
      unsigned q = (unsigned)qw[(size_t)(qr0 + r) * HID + gc];
      float s = sc[(size_t)g * HID + gc];
      unsigned zq = (unsigned)qz[(size_t)g * (HID >> 3) + (gc >> 3)];
      float zs = ((float)((zq >> ((gc & 7) * 4)) & 15u) + 1.0f) * s;
      s16x8 o;
#pragma unroll
      for (int j = 0; j < 8; ++j)
        o[j] = f2bf(fmaf((float)((q >> (4 * j)) & 15u), s, -zs));
      *(s16x8*)&tile[n * 72 + r * 8] = o;
    }
    __syncthreads();
    int n = tid >> 2;
#pragma unroll
    for (int i = 0; i < 2; ++i) {
      int c = (tid & 3) + i * 4;
      *(s16x8*)&wt[(size_t)(n0 + n) * HID + k0 + c * 8] = *(const s16x8*)&tile[n * 72 + c * 8];
    }
  }
}

// ---------------- RMSNorm only (for x2) ----------------
__global__ __launch_bounds__(256) void rmsnorm_kernel(const float* __restrict__ x,
                                                      const float* __restrict__ w,
                                                      short* __restrict__ out) {
  int row = blockIdx.x;
  const float* xr = x + (size_t)row * HID;
  short* orow = out + (size_t)row * HID;
  int tid = threadIdx.x;
  f32x4 v[4];
  float ss = 0.f;
#pragma unroll
  for (int i = 0; i < 4; ++i) {
    v[i] = ((const f32x4*)xr)[i * 256 + tid];
    ss += v[i][0] * v[i][0] + v[i][1] * v[i][1] + v[i][2] * v[i][2] + v[i][3] * v[i][3];
  }
#pragma unroll
  for (int off = 32; off > 0; off >>= 1) ss += __shfl_xor(ss, off);
  __shared__ float psum[4];
  if ((tid & 63) == 0) psum[tid >> 6] = ss;
  __syncthreads();
  float tot = psum[0] + psum[1] + psum[2] + psum[3];
  float r = rsqrtf(tot * (1.0f / (float)HID) + 1e-6f);
#pragma unroll
  for (int i = 0; i < 4; ++i) {
    int base = (i * 256 + tid) * 4;
    s16x4 o;
#pragma unroll
    for (int j = 0; j < 4; ++j) o[j] = f2bf(v[i][j] * r * w[base + j]);
    *(s16x4*)&orow[base] = o;
  }
}

// -------- paired kernel: [0,gtot) = GEMM blocks, [gtot,..) = dequant blocks --------
// GEMM: C = A[M][lda] @ BT[128*gnx][ldb]^T, tiles 128x128, m97 structure, 32KB LDS
// so gemm blocks and dequant blocks co-reside on a CU (dq latency hidden).
//   OMODE 0: bf16 store; 1: f32 store base+acc; 2: f32 C += acc; 3: C=f2bf(silu(C)*acc)
template <int OMODE>
__global__ __launch_bounds__(256) void paired_kernel(
    const short* __restrict__ A, int lda,
    const short* __restrict__ BT, int ldb,
    void* __restrict__ Cv, int ldc,
    const float* __restrict__ base, int Kext,
    int gnx, int gny,
    const int* __restrict__ qw, const int* __restrict__ qz,
    const float* __restrict__ sc, short* __restrict__ wt,
    int N, int noff, int dnx, int dqld) {
  __shared__ short sm[4 * 4096];  // 32KB: As[2][4096] | Bs[2][4096]; dq reuses front
  int bid = blockIdx.x;
  int gtot = gnx * gny;
  int tid = threadIdx.x;
  if (bid < gtot) {
    // ---------------- GEMM ----------------
    int cpx = gtot >> 3;                       // gtot always %8==0 here
    int swz = (bid & 7) * cpx + (bid >> 3);    // XCD-contiguous chunks
    int bn = swz % gnx, bm = swz / gnx;
    int lane = tid & 63, wv = tid >> 6;
    int wr = wv >> 1, wc = wv & 1;
    f32x4 acc[4][4] = {};
    int nk = Kext >> 5;
    int lr = lane >> 2, lc = lane & 3;
    const short* Abase = A + (size_t)(bm * 128) * lda;
    const short* Bbase = BT + (size_t)(bn * 128) * ldb;
    short* As0 = sm;
    short* Bs0 = sm + 8192;

    auto stage = [&](int buf, int t) {
      int k0 = t << 5;
#pragma unroll
      for (int i = 0; i < 2; ++i) {
        int r = i * 64 + wv * 16 + lr;
        gload_lds16(Abase + (size_t)r * lda + k0 + lc * 8, As0 + buf * 4096 + i * 2048 + wv * 512);
        gload_lds16(Bbase + (size_t)r * ldb + k0 + lc * 8, Bs0 + buf * 4096 + i * 2048 + wv * 512);
      }
    };
    auto compute = [&](int buf) {
      int kc = (lane >> 4) * 8;
      int ra = wr * 64 + (lane & 15);
      int rb = wc * 64 + (lane & 15);
      s16x8 af[4], bfr[4];
#pragma unroll
      for (int m = 0; m < 4; ++m) af[m] = *(const s16x8*)&As0[buf * 4096 + (ra + m * 16) * 32 + kc];
#pragma unroll
      for (int n = 0; n < 4; ++n) bfr[n] = *(const s16x8*)&Bs0[buf * 4096 + (rb + n * 16) * 32 + kc];
#pragma unroll
      for (int m = 0; m < 4; ++m)
#pragma unroll
        for (int n = 0; n < 4; ++n) acc[m][n] = mfma16(af[m], bfr[n], acc[m][n]);
    };

    stage(0, 0);
    __syncthreads();
    for (int t = 0; t < nk; ++t) {
      if (t + 1 < nk) stage((t + 1) & 1, t + 1);
      compute(t & 1);
      __syncthreads();
    }

    int row0 = bm * 128 + wr * 64 + ((lane >> 4) << 2);
    int col0 = bn * 128 + wc * 64 + (lane & 15);
#pragma unroll
    for (int m = 0; m < 4; ++m)
#pragma unroll
      for (int n = 0; n < 4; ++n)
#pragma unroll
        for (int j = 0; j < 4; ++j) {
          size_t idx = (size_t)(row0 + m * 16 + j) * ldc + col0 + n * 16;
          if (OMODE == 0)      ((short*)Cv)[idx] = f2bf(acc[m][n][j]);
          else if (OMODE == 1) ((float*)Cv)[idx] = base[idx] + acc[m][n][j];
          else if (OMODE == 2) ((float*)Cv)[idx] = ((float*)Cv)[idx] + acc[m][n][j];
          else {  // silu(gate)*up, gate preloaded in Cv as bf16
            short* C = (short*)Cv;
            float g = bf2f(C[idx]);
            float sl = g / (1.f + __expf(-g));
            C[idx] = f2bf(sl * acc[m][n][j]);
          }
        }
  } else {
    // ---------------- dequant (co-resident with gemm blocks) ----------------
    int id = bid - gtot;
    int n0 = (id % dnx) * 64;
    int k0 = (id / dnx) * 64;
    int g = k0 >> 7;
    int qr0 = k0 >> 3;
#pragma unroll
    for (int i = 0; i < 2; ++i) {
      int idx = tid + i * 256;
      int r = idx >> 6;
      int n = idx & 63;
      int gc = noff + n0 + n;
      unsigned q = (unsigned)qw[(size_t)(qr0 + r) * N + gc];
      float s = sc[(size_t)g * N + gc];
      unsigned zq = (unsigned)qz[(size_t)g * (N >> 3) + (gc >> 3)];
      float zs = ((float)((zq >> ((gc & 7) * 4)) & 15u) + 1.0f) * s;
      s16x8 o;
#pragma unroll
      for (int j = 0; j < 8; ++j)
        o[j] = f2bf(fmaf((float)((q >> (4 * j)) & 15u), s, -zs));
      *(s16x8*)&sm[n * 72 + r * 8] = o;
    }
    __syncthreads();
    int n = tid >> 2;
#pragma unroll
    for (int i = 0; i < 2; ++i) {
      int c = (tid & 3) + i * 4;
      *(s16x8*)&wt[(size_t)(n0 + n) * dqld + k0 + c * 8] = *(const s16x8*)&sm[n * 72 + c * 8];
    }
  }
}

// ---------------- RoPE: one block per position s, q+k, all heads ----------------
__global__ __launch_bounds__(256) void rope_kernel(short* __restrict__ q,
                                                   short* __restrict__ k,
                                                   const float* __restrict__ sp,
                                                   const float* __restrict__ cp) {
  int s = blockIdx.x, t = threadIdx.x;
  int g0 = t * 16;
  int hd = g0 & 127;
  bool low = (g0 & 64) == 0;
  size_t own = (size_t)s * HID + g0;
  size_t par = (size_t)s * HID + (g0 ^ 64);
  float cs[16], sn[16];
#pragma unroll
  for (int i = 0; i < 16; ++i) {
    cs[i] = cp[s * HD + hd + i];
    sn[i] = sp[s * HD + hd + i];
  }
  s16x8 qa0 = *(s16x8*)&q[own], qa1 = *(s16x8*)&q[own + 8];
  s16x8 qb0 = *(s16x8*)&q[par], qb1 = *(s16x8*)&q[par + 8];
  s16x8 ka0 = *(s16x8*)&k[own], ka1 = *(s16x8*)&k[own + 8];
  s16x8 kb0 = *(s16x8*)&k[par], kb1 = *(s16x8*)&k[par + 8];
  s16x8 qo0, qo1, ko0, ko1;
#pragma unroll
  for (int i = 0; i < 8; ++i) {
    float rq0 = low ? -bf2f(qb0[i]) : bf2f(qb0[i]);
    float rq1 = low ? -bf2f(qb1[i]) : bf2f(qb1[i]);
    float rk0 = low ? -bf2f(kb0[i]) : bf2f(kb0[i]);
    float rk1 = low ? -bf2f(kb1[i]) : bf2f(kb1[i]);
    qo0[i] = f2bf(bf2f(qa0[i]) * cs[i] + rq0 * sn[i]);
    qo1[i] = f2bf(bf2f(qa1[i]) * cs[i + 8] + rq1 * sn[i + 8]);
    ko0[i] = f2bf(bf2f(ka0[i]) * cs[i] + rk0 * sn[i]);
    ko1[i] = f2bf(bf2f(ka1[i]) * cs[i + 8] + rk1 * sn[i + 8]);
  }
  __syncthreads();
  *(s16x8*)&q[own] = qo0; *(s16x8*)&q[own + 8] = qo1;
  *(s16x8*)&k[own] = ko0; *(s16x8*)&k[own + 8] = ko1;
}

// ---------------- Flash attention (causal), bf16 in/out ----------------
// Single-buffer Kl (issueK after barrier-1, drained by barrier-2's vmcnt) cuts
// LDS 69.6K -> 52.8K => 3 blocks/CU. Session lesson: co-residency beats
// intra-block prefetch depth on this chip. Balanced 1D grid (round-16 proven).
__global__ __launch_bounds__(256, 3) void attn_kernel(const short* __restrict__ qb,
                                                      const short* __restrict__ kb,
                                                      const short* __restrict__ vb,
                                                      short* __restrict__ ob) {
  int L = blockIdx.x;
  int half = L >> 8;
  int idx = L & 255;
  int qt = half ? 15 - (idx & 15) : (idx & 15);
  int h  = (half << 4) + (idx >> 4);
  int tid = threadIdx.x, lane = tid & 63, wv = tid >> 6;
  __shared__ short Kl[64 * 128];     // [kv][d], 16B-chunk XOR-swizzled (single buf)
  __shared__ short Vl[128 * 72];     // [d][kv] padded + XOR-swizzled
  __shared__ short Pl[4][32 * 72];   // per-wave [q][kv] padded
  int q0 = qt * 128 + wv * 32;
  s16x8 qf[2][4];
#pragma unroll
  for (int m = 0; m < 2; ++m)
#pragma unroll
    for (int kf = 0; kf < 4; ++kf) {
      int r = q0 + m * 16 + (lane & 15);
      int d = kf * 32 + (lane >> 4) * 8;
      qf[m][kf] = *(const s16x8*)&qb[(size_t)r * HID + h * HD + d];
    }
  f32x4 o[2][8] = {};
  float mrow[2][4], lrow[2][4];
#pragma unroll
  for (int m = 0; m < 2; ++m)
#pragma unroll
    for (int j = 0; j < 4; ++j) { mrow[m][j] = -1e30f; lrow[m][j] = 0.f; }

  auto issueK = [&](int kv0) {
#pragma unroll
    for (int i = 0; i < 4; ++i) {
      int kvL0 = wv * 4 + i * 16;              // wave-uniform row base
      int kvL = kvL0 + (lane >> 4);
      int csw = (lane & 15) ^ (kvL & 7);
      gload_lds16(kb + (size_t)(kv0 + kvL) * HID + h * HD + csw * 8,
                  &Kl[kvL0 * 128]);
    }
  };
  auto loadV = [&](int kv0, s16x8* vr) {
#pragma unroll
    for (int i = 0; i < 4; ++i) {
      int cid = tid + i * 256;
      int kv = cid >> 4, c = cid & 15;
      vr[i] = *(const s16x8*)(vb + (size_t)(kv0 + kv) * HID + h * HD + c * 8);
    }
  };
  auto storeV = [&](const s16x8* vr) {
#pragma unroll
    for (int i = 0; i < 4; ++i) {
      int cid = tid + i * 256;
      int kv = cid >> 4, c = cid & 15;
      int kvs = kv ^ ((c & 7) << 3);
#pragma unroll
      for (int j = 0; j < 8; ++j) Vl[(c * 8 + j) * 72 + kvs] = vr[i][j];
    }
  };

  const float scale = 0.08838834764831845f;
  int kv_end = qt * 128 + 128;
  s16x8 vrb[4];
  issueK(0);
  loadV(0, vrb);
  storeV(vrb);
  __syncthreads();   // drains issueK's vmcnt too
  for (int kv0 = 0; kv0 < kv_end; kv0 += 64) {
    bool more = kv0 + 64 < kv_end;
    if (more) loadV(kv0 + 64, vrb);  // V reg-prefetch under compute

    f32x4 sfr[2][4] = {};
    __builtin_amdgcn_s_setprio(1);
#pragma unroll
    for (int nf = 0; nf < 4; ++nf) {
      s16x8 kfr[4];
      int kvr = nf * 16 + (lane & 15);
#pragma unroll
      for (int kf = 0; kf < 4; ++kf) {
        int cc = (kf * 4 + (lane >> 4)) ^ (kvr & 7);
        kfr[kf] = *(const s16x8*)((const char*)Kl + kvr * 256 + cc * 16);
      }
#pragma unroll
      for (int m = 0; m < 2; ++m)
#pragma unroll
        for (int kf = 0; kf < 4; ++kf) sfr[m][nf] = mfma16(qf[m][kf], kfr[kf], sfr[m][nf]);
    }
    __builtin_amdgcn_s_setprio(0);
#pragma unroll
    for (int m = 0; m < 2; ++m)
#pragma unroll
      for (int j = 0; j < 4; ++j) {
        int qrow = q0 + m * 16 + (lane >> 4) * 4 + j;
        float pm = -1e30f;
#pragma unroll
        for (int nf = 0; nf < 4; ++nf) {
          int kvc = kv0 + nf * 16 + (lane & 15);
          float v = sfr[m][nf][j] * scale;
          v = (kvc <= qrow) ? v : -1e30f;
          sfr[m][nf][j] = v;
          pm = fmaxf(pm, v);
        }
#pragma unroll
        for (int off = 1; off < 16; off <<= 1) pm = fmaxf(pm, __shfl_xor(pm, off));
        float mnew = fmaxf(mrow[m][j], pm);
        float alpha = __expf(mrow[m][j] - mnew);
        mrow[m][j] = mnew;
        float rs = 0.f;
#pragma unroll
        for (int nf = 0; nf < 4; ++nf) {
          float pv = __expf(sfr[m][nf][j] - mnew);
          sfr[m][nf][j] = pv;
          rs += pv;
        }
#pragma unroll
        for (int off = 1; off < 16; off <<= 1) rs += __shfl_xor(rs, off);
        lrow[m][j] = lrow[m][j] * alpha + rs;
#pragma unroll
        for (int nd = 0; nd < 8; ++nd) o[m][nd][j] *= alpha;
      }
#pragma unroll
    for (int m = 0; m < 2; ++m)
#pragma unroll
      for (int nf = 0; nf < 4; ++nf)
#pragma unroll
        for (int j = 0; j < 4; ++j)
          Pl[wv][(m * 16 + (lane >> 4) * 4 + j) * 72 + nf * 16 + (lane & 15)] =
              f2bf(sfr[m][nf][j]);
    s16x8 pa[2][2];
#pragma unroll
    for (int m = 0; m < 2; ++m)
#pragma unroll
      for (int kf = 0; kf < 2; ++kf)
        pa[m][kf] = *(const s16x8*)&Pl[wv][(m * 16 + (lane & 15)) * 72 + kf * 32 + (lane >> 4) * 8];
    __builtin_amdgcn_s_setprio(1);
#pragma unroll
    for (int nd = 0; nd < 8; ++nd) {
      s16x8 vf[2];
      int drow = nd * 16 + (lane & 15);
      int key = ((drow >> 3) & 7) << 3;
#pragma unroll
      for (int kf = 0; kf < 2; ++kf)
        vf[kf] = *(const s16x8*)&Vl[drow * 72 + ((kf * 32 + (lane >> 4) * 8) ^ key)];
#pragma unroll
      for (int m = 0; m < 2; ++m)
#pragma unroll
        for (int kf = 0; kf < 2; ++kf) o[m][nd] = mfma16(pa[m][kf], vf[kf], o[m][nd]);
    }
    __builtin_amdgcn_s_setprio(0);
    __syncthreads();                 // barrier1: all waves done reading Kl/Vl
    if (more) { issueK(kv0 + 64); storeV(vrb); }
    __syncthreads();                 // barrier2: per-wave vmcnt drain => Kl ready
  }
  float li[2][4];
#pragma unroll
  for (int m = 0; m < 2; ++m)
#pragma unroll
    for (int j = 0; j < 4; ++j) li[m][j] = 1.0f / lrow[m][j];
#pragma unroll
  for (int m = 0; m < 2; ++m)
#pragma unroll
    for (int nd = 0; nd < 8; ++nd)
#pragma unroll
      for (int j = 0; j < 4; ++j) {
        int r = q0 + m * 16 + (lane >> 4) * 4 + j;
        int c = h * HD + nd * 16 + (lane & 15);
        ob[(size_t)r * HID + c] = f2bf(o[m][nd][j] * li[m][j]);
      }
}

extern "C" void kernel_launch(void* const* d_in, const int* in_sizes, int n_in,
                              void* d_out, int out_size, void* d_ws, size_t ws_size,
                              hipStream_t stream) {
  const int* qw[7]; const int* qz[7]; const float* sc[7];
  for (int i = 0; i < 7; ++i) {
    qw[i] = (const int*)d_in[i * 3 + 0];
    qz[i] = (const int*)d_in[i * 3 + 1];
    sc[i] = (const float*)d_in[i * 3 + 2];
  }
  const float* hin  = (const float*)d_in[21];
  const float* ln1  = (const float*)d_in[22];
  const float* ln2  = (const float*)d_in[23];
  const float* sinp = (const float*)d_in[24];
  const float* cosp = (const float*)d_in[25];
  float* out = (float*)d_out;        // h2 lives here from o-proj onward

  char* ws = (char*)d_ws;
  const size_t MB = 1024 * 1024;
  // peak ws usage: 128 MB (proven-safe; round-8 layout verbatim)
  short* XB    = (short*)(ws);              // [0,16)  x1 then x2, bf16
  short* WA    = (short*)(ws + 16 * MB);    // [16,48)  weight buf A (32MB)
  short* WB    = (short*)(ws + 48 * MB);    // [48,80)  weight buf B (32MB)
  short* KB    = (short*)(ws + 80 * MB);    // [80,96)
  short* VB    = (short*)(ws + 96 * MB);    // [96,112)
  short* OB    = (short*)(ws + 112 * MB);   // [112,128)
  short* GATEB = (short*)(ws + 80 * MB);    // [80,123) aliases KB/VB/OB after attn
  short* QBd   = (short*)d_out;             // q bf16 in d_out[0:16MB) (dead until o-proj)

  dim3 blk(256);

  // L0: x1 = rms(h, ln1)  ||  dequant Wq -> WA  (merged launch)
  rmsdq_kernel<<<S_LEN + 4096, blk, 0, stream>>>(hin, ln1, XB, qw[0], qz[0], sc[0], WA, S_LEN);
  // L2: q = x1@Wq -> QBd  || dequant Wk -> WB
  paired_kernel<0><<<512 + 4096, blk, 0, stream>>>(XB, HID, WA, HID, QBd, HID, nullptr, HID,
                                                   32, 16, qw[1], qz[1], sc[1], WB, HID, 0, 64, HID);
  // L3: k -> KB || dequant Wv -> WA
  paired_kernel<0><<<512 + 4096, blk, 0, stream>>>(XB, HID, WB, HID, KB, HID, nullptr, HID,
                                                   32, 16, qw[2], qz[2], sc[2], WA, HID, 0, 64, HID);
  // L4: v -> VB || dequant Wo -> WB
  paired_kernel<0><<<512 + 4096, blk, 0, stream>>>(XB, HID, WA, HID, VB, HID, nullptr, HID,
                                                   32, 16, qw[3], qz[3], sc[3], WB, HID, 0, 64, HID);
  // L5/L6: rope + attention (balanced 1D grid)
  rope_kernel<<<S_LEN, blk, 0, stream>>>(QBd, KB, sinp, cosp);
  attn_kernel<<<512, blk, 0, stream>>>(QBd, KB, VB, OB);
  // L7: h2 = h + o@Wo -> d_out || dequant gate_c0 -> WA
  paired_kernel<1><<<512 + 4096, blk, 0, stream>>>(OB, HID, WB, HID, out, HID, hin, HID,
                                                   32, 16, qw[4], qz[4], sc[4], WA, INTER, 0, 64, HID);
  // L8: x2 = rms(h2, ln2)
  rmsnorm_kernel<<<S_LEN, blk, 0, stream>>>(out, ln2, XB);

  // MLP: per chunk c: gate_c (OMODE0) then up_c (OMODE3: y=silu(gate)*up in place),
  // each paired with the next dequant. Buffers alternate WA/WB strictly.
  // L9:  gate_c0 (WA) || dq up_c0 -> WB
  paired_kernel<0><<<512 + 4096, blk, 0, stream>>>(XB, HID, WA, HID, GATEB + 0, INTER, nullptr, HID,
                                                   32, 16, qw[5], qz[5], sc[5], WB, INTER, 0, 64, HID);
  // L10: up_c0 (WB) || dq gate_c1 -> WA
  paired_kernel<3><<<512 + 4096, blk, 0, stream>>>(XB, HID, WB, HID, GATEB + 0, INTER, nullptr, HID,
                                                   32, 16, qw[4], qz[4], sc[4], WA, INTER, 4096, 64, HID);
  // L11: gate_c1 (WA) || dq up_c1 -> WB
  paired_kernel<0><<<512 + 4096, blk, 0, stream>>>(XB, HID, WA, HID, GATEB + 4096, INTER, nullptr, HID,
                                                   32, 16, qw[5], qz[5], sc[5], WB, INTER, 4096, 64, HID);
  // L12: up_c1 (WB) || dq gate_c2 -> WA (2816 cols -> 44x64 blocks)
  paired_kernel<3><<<512 + 2816, blk, 0, stream>>>(XB, HID, WB, HID, GATEB + 4096, INTER, nullptr, HID,
                                                   32, 16, qw[4], qz[4], sc[4], WA, INTER, 8192, 44, HID);
  // L13: gate_c2 (WA, gnx=22) || dq up_c2 -> WB
  paired_kernel<0><<<352 + 2816, blk, 0, stream>>>(XB, HID, WA, HID, GATEB + 8192, INTER, nullptr, HID,
                                                   22, 16, qw[5], qz[5], sc[5], WB, INTER, 8192, 44, HID);
  // L14: up_c2 (WB, gnx=22) || dq down_c0 -> WA
  paired_kernel<3><<<352 + 4096, blk, 0, stream>>>(XB, HID, WB, HID, GATEB + 8192, INTER, nullptr, HID,
                                                   22, 16, qw[6], qz[6], sc[6], WA, HID, 0, 64, 4096);
  // L15: down_c0: out += y[:,0:4096]@Wd0 (WA) || dq down_c1 -> WB
  paired_kernel<2><<<512 + 4096, blk, 0, stream>>>(GATEB + 0, INTER, WA, 4096, out, HID, nullptr, 4096,
                                                   32, 16,
                                                   qw[6] + (size_t)(4096 >> 3) * HID,
                                                   qz[6] + (size_t)(4096 >> 7) * (HID / 8),
                                                   sc[6] + (size_t)(4096 >> 7) * HID,
                                                   WB, HID, 0, 64, 4096);
  // L16: down_c1 (WB) || dq down_c2 -> WA (2816 k -> 64x44 blocks)
  paired_kernel<2><<<512 + 2816, blk, 0, stream>>>(GATEB + 4096, INTER, WB, 4096, out, HID, nullptr, 4096,
                                                   32, 16,
                                                   qw[6] + (size_t)(8192 >> 3) * HID,
                                                   qz[6] + (size_t)(8192 >> 7) * (HID / 8),
                                                   sc[6] + (size_t)(8192 >> 7) * HID,
                                                   WA, HID, 0, 64, 2816);
  // L17: down_c2 (WA, Kext=2816), pure gemm
  paired_kernel<2><<<512, blk, 0, stream>>>(GATEB + 8192, INTER, WA, 2816, out, HID, nullptr, 2816,
                                            32, 16, nullptr, nullptr, nullptr, nullptr, HID, 0, 1, HID);
}

// Round 18
// 1335.835 us; speedup vs baseline: 1.1787x; 1.1787x over previous
//
#include <hip/hip_runtime.h>
#include <cstdint>
#include <cstddef>

#define S_LEN 2048
#define HID   4096
#define INTER 11008
#define NHEADS 32
#define HD    128

typedef __attribute__((ext_vector_type(4))) float  f32x4;
typedef __attribute__((ext_vector_type(8))) __bf16 bf16x8;
typedef __attribute__((ext_vector_type(8))) short  s16x8;
typedef __attribute__((ext_vector_type(4))) short  s16x4;

__device__ __forceinline__ float bf2f(short s) {
  unsigned u = ((unsigned)(unsigned short)s) << 16;
  return __builtin_bit_cast(float, u);
}
__device__ __forceinline__ short f2bf(float f) {
  unsigned u = __builtin_bit_cast(unsigned, f);
  u += 0x7FFFu + ((u >> 16) & 1u);
  return (short)(u >> 16);
}
__device__ __forceinline__ f32x4 mfma16(s16x8 a, s16x8 b, f32x4 c) {
  return __builtin_amdgcn_mfma_f32_16x16x32_bf16(
      __builtin_bit_cast(bf16x8, a), __builtin_bit_cast(bf16x8, b), c, 0, 0, 0);
}
__device__ __forceinline__ void gload_lds16(const void* g, void* l) {
  __builtin_amdgcn_global_load_lds(
      (const __attribute__((address_space(1))) void*)g,
      (__attribute__((address_space(3))) void*)l, 16, 0, 0);
}

// ---- merged: [0,nrows) rmsnorm rows; [nrows,..) Wq dequant tiles (64x64) ----
__global__ __launch_bounds__(256) void rmsdq_kernel(const float* __restrict__ x,
                                                    const float* __restrict__ w,
                                                    short* __restrict__ xout,
                                                    const int* __restrict__ qw,
                                                    const int* __restrict__ qz,
                                                    const float* __restrict__ sc,
                                                    short* __restrict__ wt,
                                                    int nrows) {
  __shared__ short tile[4608];
  __shared__ float psum[4];
  int bid = blockIdx.x;
  int tid = threadIdx.x;
  if (bid < nrows) {
    const float* xr = x + (size_t)bid * HID;
    short* orow = xout + (size_t)bid * HID;
    f32x4 v[4];
    float ss = 0.f;
#pragma unroll
    for (int i = 0; i < 4; ++i) {
      v[i] = ((const f32x4*)xr)[i * 256 + tid];
      ss += v[i][0] * v[i][0] + v[i][1] * v[i][1] + v[i][2] * v[i][2] + v[i][3] * v[i][3];
    }
#pragma unroll
    for (int off = 32; off > 0; off >>= 1) ss += __shfl_xor(ss, off);
    if ((tid & 63) == 0) psum[tid >> 6] = ss;
    __syncthreads();
    float tot = psum[0] + psum[1] + psum[2] + psum[3];
    float r = rsqrtf(tot * (1.0f / (float)HID) + 1e-6f);
#pragma unroll
    for (int i = 0; i < 4; ++i) {
      int base = (i * 256 + tid) * 4;
      s16x4 o;
#pragma unroll
      for (int j = 0; j < 4; ++j) o[j] = f2bf(v[i][j] * r * w[base + j]);
      *(s16x4*)&orow[base] = o;
    }
  } else {
    int id = bid - nrows;
    int n0 = (id & 63) * 64;
    int k0 = (id >> 6) * 64;
    int g = k0 >> 7;
    int qr0 = k0 >> 3;
#pragma unroll
    for (int i = 0; i < 2; ++i) {
      int idx = tid + i * 256;
      int r = idx >> 6;
      int n = idx & 63;
      int gc = n0 + n;
      unsigned q = (unsigned)qw[(size_t)(qr0 + r) * HID + gc];
      float s = sc[(size_t)g * HID + gc];
      unsigned zq = (unsigned)qz[(size_t)g * (HID >> 3) + (gc >> 3)];
      float zs = ((float)((zq >> ((gc & 7) * 4)) & 15u) + 1.0f) * s;
      s16x8 o;
#pragma unroll
      for (int j = 0; j < 8; ++j)
        o[j] = f2bf(fmaf((float)((q >> (4 * j)) & 15u), s, -zs));
      *(s16x8*)&tile[n * 72 + r * 8] = o;
    }
    __syncthreads();
    int n = tid >> 2;
#pragma unroll
    for (int i = 0; i < 2; ++i) {
      int c = (tid & 3) + i * 4;
      *(s16x8*)&wt[(size_t)(n0 + n) * HID + k0 + c * 8] = *(const s16x8*)&tile[n * 72 + c * 8];
    }
  }
}

// ---------------- RMSNorm only (for x2) ----------------
__global__ __launch_bounds__(256) void rmsnorm_kernel(const float* __restrict__ x,
                                                      const float* __restrict__ w,
                                                      short* __restrict__ out) {
  int row = blockIdx.x;
  const float* xr = x + (size_t)row * HID;
  short* orow = out + (size_t)row * HID;
  int tid = threadIdx.x;
  f32x4 v[4];
  float ss = 0.f;
#pragma unroll
  for (int i = 0; i < 4; ++i) {
    v[i] = ((const f32x4*)xr)[i * 256 + tid];
    ss += v[i][0] * v[i][0] + v[i][1] * v[i][1] + v[i][2] * v[i][2] + v[i][3] * v[i][3];
  }
#pragma unroll
  for (int off = 32; off > 0; off >>= 1) ss += __shfl_xor(ss, off);
  __shared__ float psum[4];
  if ((tid & 63) == 0) psum[tid >> 6] = ss;
  __syncthreads();
  float tot = psum[0] + psum[1] + psum[2] + psum[3];
  float r = rsqrtf(tot * (1.0f / (float)HID) + 1e-6f);
#pragma unroll
  for (int i = 0; i < 4; ++i) {
    int base = (i * 256 + tid) * 4;
    s16x4 o;
#pragma unroll
    for (int j = 0; j < 4; ++j) o[j] = f2bf(v[i][j] * r * w[base + j]);
    *(s16x4*)&orow[base] = o;
  }
}

// -------- paired kernel: [0,gtot) = GEMM blocks, [gtot,..) = dequant blocks --------
// GEMM: C = A[M][lda] @ BT[128*gnx][ldb]^T, tiles 128x128, m97 structure, 32KB LDS
// so gemm blocks and dequant blocks co-reside on a CU (dq latency hidden).
//   OMODE 0: bf16 store; 1: f32 store base+acc; 2: f32 C += acc; 3: C=f2bf(silu(C)*acc)
template <int OMODE>
__global__ __launch_bounds__(256) void paired_kernel(
    const short* __restrict__ A, int lda,
    const short* __restrict__ BT, int ldb,
    void* __restrict__ Cv, int ldc,
    const float* __restrict__ base, int Kext,
    int gnx, int gny,
    const int* __restrict__ qw, const int* __restrict__ qz,
    const float* __restrict__ sc, short* __restrict__ wt,
    int N, int noff, int dnx, int dqld) {
  __shared__ short sm[4 * 4096];  // 32KB: As[2][4096] | Bs[2][4096]; dq reuses front
  int bid = blockIdx.x;
  int gtot = gnx * gny;
  int tid = threadIdx.x;
  if (bid < gtot) {
    // ---------------- GEMM ----------------
    int cpx = gtot >> 3;                       // gtot always %8==0 here
    int swz = (bid & 7) * cpx + (bid >> 3);    // XCD-contiguous chunks
    int bn = swz % gnx, bm = swz / gnx;
    int lane = tid & 63, wv = tid >> 6;
    int wr = wv >> 1, wc = wv & 1;
    f32x4 acc[4][4] = {};
    int nk = Kext >> 5;
    int lr = lane >> 2, lc = lane & 3;
    const short* Abase = A + (size_t)(bm * 128) * lda;
    const short* Bbase = BT + (size_t)(bn * 128) * ldb;
    short* As0 = sm;
    short* Bs0 = sm + 8192;

    auto stage = [&](int buf, int t) {
      int k0 = t << 5;
#pragma unroll
      for (int i = 0; i < 2; ++i) {
        int r = i * 64 + wv * 16 + lr;
        gload_lds16(Abase + (size_t)r * lda + k0 + lc * 8, As0 + buf * 4096 + i * 2048 + wv * 512);
        gload_lds16(Bbase + (size_t)r * ldb + k0 + lc * 8, Bs0 + buf * 4096 + i * 2048 + wv * 512);
      }
    };
    auto compute = [&](int buf) {
      int kc = (lane >> 4) * 8;
      int ra = wr * 64 + (lane & 15);
      int rb = wc * 64 + (lane & 15);
      s16x8 af[4], bfr[4];
#pragma unroll
      for (int m = 0; m < 4; ++m) af[m] = *(const s16x8*)&As0[buf * 4096 + (ra + m * 16) * 32 + kc];
#pragma unroll
      for (int n = 0; n < 4; ++n) bfr[n] = *(const s16x8*)&Bs0[buf * 4096 + (rb + n * 16) * 32 + kc];
#pragma unroll
      for (int m = 0; m < 4; ++m)
#pragma unroll
        for (int n = 0; n < 4; ++n) acc[m][n] = mfma16(af[m], bfr[n], acc[m][n]);
    };

    stage(0, 0);
    __syncthreads();
    for (int t = 0; t < nk; ++t) {
      if (t + 1 < nk) stage((t + 1) & 1, t + 1);
      compute(t & 1);
      __syncthreads();
    }

    int row0 = bm * 128 + wr * 64 + ((lane >> 4) << 2);
    int col0 = bn * 128 + wc * 64 + (lane & 15);
#pragma unroll
    for (int m = 0; m < 4; ++m)
#pragma unroll
      for (int n = 0; n < 4; ++n)
#pragma unroll
        for (int j = 0; j < 4; ++j) {
          size_t idx = (size_t)(row0 + m * 16 + j) * ldc + col0 + n * 16;
          if (OMODE == 0)      ((short*)Cv)[idx] = f2bf(acc[m][n][j]);
          else if (OMODE == 1) ((float*)Cv)[idx] = base[idx] + acc[m][n][j];
          else if (OMODE == 2) ((float*)Cv)[idx] = ((float*)Cv)[idx] + acc[m][n][j];
          else {  // silu(gate)*up, gate preloaded in Cv as bf16
            short* C = (short*)Cv;
            float g = bf2f(C[idx]);
            float sl = g / (1.f + __expf(-g));
            C[idx] = f2bf(sl * acc[m][n][j]);
          }
        }
  } else {
    // ---------------- dequant (co-resident with gemm blocks) ----------------
    int id = bid - gtot;
    int n0 = (id % dnx) * 64;
    int k0 = (id / dnx) * 64;
    int g = k0 >> 7;
    int qr0 = k0 >> 3;
#pragma unroll
    for (int i = 0; i < 2; ++i) {
      int idx = tid + i * 256;
      int r = idx >> 6;
      int n = idx & 63;
      int gc = noff + n0 + n;
      unsigned q = (unsigned)qw[(size_t)(qr0 + r) * N + gc];
      float s = sc[(size_t)g * N + gc];
      unsigned zq = (unsigned)qz[(size_t)g * (N >> 3) + (gc >> 3)];
      float zs = ((float)((zq >> ((gc & 7) * 4)) & 15u) + 1.0f) * s;
      s16x8 o;
#pragma unroll
      for (int j = 0; j < 8; ++j)
        o[j] = f2bf(fmaf((float)((q >> (4 * j)) & 15u), s, -zs));
      *(s16x8*)&sm[n * 72 + r * 8] = o;
    }
    __syncthreads();
    int n = tid >> 2;
#pragma unroll
    for (int i = 0; i < 2; ++i) {
      int c = (tid & 3) + i * 4;
      *(s16x8*)&wt[(size_t)(n0 + n) * dqld + k0 + c * 8] = *(const s16x8*)&sm[n * 72 + c * 8];
    }
  }
}

// ---------------- RoPE: one block per position s, q+k, all heads ----------------
__global__ __launch_bounds__(256) void rope_kernel(short* __restrict__ q,
                                                   short* __restrict__ k,
                                                   const float* __restrict__ sp,
                                                   const float* __restrict__ cp) {
  int s = blockIdx.x, t = threadIdx.x;
  int g0 = t * 16;
  int hd = g0 & 127;
  bool low = (g0 & 64) == 0;
  size_t own = (size_t)s * HID + g0;
  size_t par = (size_t)s * HID + (g0 ^ 64);
  float cs[16], sn[16];
#pragma unroll
  for (int i = 0; i < 16; ++i) {
    cs[i] = cp[s * HD + hd + i];
    sn[i] = sp[s * HD + hd + i];
  }
  s16x8 qa0 = *(s16x8*)&q[own], qa1 = *(s16x8*)&q[own + 8];
  s16x8 qb0 = *(s16x8*)&q[par], qb1 = *(s16x8*)&q[par + 8];
  s16x8 ka0 = *(s16x8*)&k[own], ka1 = *(s16x8*)&k[own + 8];
  s16x8 kb0 = *(s16x8*)&k[par], kb1 = *(s16x8*)&k[par + 8];
  s16x8 qo0, qo1, ko0, ko1;
#pragma unroll
  for (int i = 0; i < 8; ++i) {
    float rq0 = low ? -bf2f(qb0[i]) : bf2f(qb0[i]);
    float rq1 = low ? -bf2f(qb1[i]) : bf2f(qb1[i]);
    float rk0 = low ? -bf2f(kb0[i]) : bf2f(kb0[i]);
    float rk1 = low ? -bf2f(kb1[i]) : bf2f(kb1[i]);
    qo0[i] = f2bf(bf2f(qa0[i]) * cs[i] + rq0 * sn[i]);
    qo1[i] = f2bf(bf2f(qa1[i]) * cs[i + 8] + rq1 * sn[i + 8]);
    ko0[i] = f2bf(bf2f(ka0[i]) * cs[i] + rk0 * sn[i]);
    ko1[i] = f2bf(bf2f(ka1[i]) * cs[i + 8] + rk1 * sn[i + 8]);
  }
  __syncthreads();
  *(s16x8*)&q[own] = qo0; *(s16x8*)&q[own + 8] = qo1;
  *(s16x8*)&k[own] = ko0; *(s16x8*)&k[own + 8] = ko1;
}

// ---------------- Flash attention (causal), bf16 in/out ----------------
// K via global_load_lds w/ pre-swizzled source; Kl double-buffered; V
// reg-prefetch + 2-barrier store. (256,2): 128 VGPR + modest spills is the
// proven optimum (1blk spill-free=283us, 3blk heavy-spill=390us, this=141us).
// Balanced 1D grid: CU pair (L, L+256) sums to 15 KV-tiles.
__global__ __launch_bounds__(256, 2) void attn_kernel(const short* __restrict__ qb,
                                                      const short* __restrict__ kb,
                                                      const short* __restrict__ vb,
                                                      short* __restrict__ ob) {
  int L = blockIdx.x;
  int half = L >> 8;
  int idx = L & 255;
  int qt = half ? 15 - (idx & 15) : (idx & 15);
  int h  = (half << 4) + (idx >> 4);
  int tid = threadIdx.x, lane = tid & 63, wv = tid >> 6;
  __shared__ short Kl[2][64 * 128];  // [buf][kv][d], 16B-chunk XOR-swizzled
  __shared__ short Vl[128 * 72];     // [d][kv] padded + XOR-swizzled
  __shared__ short Pl[4][32 * 72];   // per-wave [q][kv] padded
  int q0 = qt * 128 + wv * 32;
  s16x8 qf[2][4];
#pragma unroll
  for (int m = 0; m < 2; ++m)
#pragma unroll
    for (int kf = 0; kf < 4; ++kf) {
      int r = q0 + m * 16 + (lane & 15);
      int d = kf * 32 + (lane >> 4) * 8;
      qf[m][kf] = *(const s16x8*)&qb[(size_t)r * HID + h * HD + d];
    }
  f32x4 o[2][8] = {};
  float mrow[2][4], lrow[2][4];
#pragma unroll
  for (int m = 0; m < 2; ++m)
#pragma unroll
    for (int j = 0; j < 4; ++j) { mrow[m][j] = -1e30f; lrow[m][j] = 0.f; }

  auto issueK = [&](int kv0, int buf) {
#pragma unroll
    for (int i = 0; i < 4; ++i) {
      int kvL0 = wv * 4 + i * 16;              // wave-uniform row base
      int kvL = kvL0 + (lane >> 4);
      int csw = (lane & 15) ^ (kvL & 7);
      gload_lds16(kb + (size_t)(kv0 + kvL) * HID + h * HD + csw * 8,
                  &Kl[buf][kvL0 * 128]);
    }
  };
  auto loadV = [&](int kv0, s16x8* vr) {
#pragma unroll
    for (int i = 0; i < 4; ++i) {
      int cid = tid + i * 256;
      int kv = cid >> 4, c = cid & 15;
      vr[i] = *(const s16x8*)(vb + (size_t)(kv0 + kv) * HID + h * HD + c * 8);
    }
  };
  auto storeV = [&](const s16x8* vr) {
#pragma unroll
    for (int i = 0; i < 4; ++i) {
      int cid = tid + i * 256;
      int kv = cid >> 4, c = cid & 15;
      int kvs = kv ^ ((c & 7) << 3);
#pragma unroll
      for (int j = 0; j < 8; ++j) Vl[(c * 8 + j) * 72 + kvs] = vr[i][j];
    }
  };

  const float scale = 0.08838834764831845f;
  int kv_end = qt * 128 + 128;
  s16x8 vra[4], vrb[4];
  issueK(0, 0);
  loadV(0, vra);
  storeV(vra);
  __syncthreads();   // drains issueK's vmcnt too
  int t = 0;
  for (int kv0 = 0; kv0 < kv_end; kv0 += 64, ++t) {
    int cb = t & 1;
    bool more = kv0 + 64 < kv_end;
    if (more) { issueK(kv0 + 64, cb ^ 1); loadV(kv0 + 64, vrb); }

    f32x4 sfr[2][4] = {};
    __builtin_amdgcn_s_setprio(1);
#pragma unroll
    for (int nf = 0; nf < 4; ++nf) {
      s16x8 kfr[4];
      int kvr = nf * 16 + (lane & 15);
#pragma unroll
      for (int kf = 0; kf < 4; ++kf) {
        int cc = (kf * 4 + (lane >> 4)) ^ (kvr & 7);
        kfr[kf] = *(const s16x8*)((const char*)&Kl[cb][0] + kvr * 256 + cc * 16);
      }
#pragma unroll
      for (int m = 0; m < 2; ++m)
#pragma unroll
        for (int kf = 0; kf < 4; ++kf) sfr[m][nf] = mfma16(qf[m][kf], kfr[kf], sfr[m][nf]);
    }
    __builtin_amdgcn_s_setprio(0);
#pragma unroll
    for (int m = 0; m < 2; ++m)
#pragma unroll
      for (int j = 0; j < 4; ++j) {
        int qrow = q0 + m * 16 + (lane >> 4) * 4 + j;
        float pm = -1e30f;
#pragma unroll
        for (int nf = 0; nf < 4; ++nf) {
          int kvc = kv0 + nf * 16 + (lane & 15);
          float v = sfr[m][nf][j] * scale;
          v = (kvc <= qrow) ? v : -1e30f;
          sfr[m][nf][j] = v;
          pm = fmaxf(pm, v);
        }
#pragma unroll
        for (int off = 1; off < 16; off <<= 1) pm = fmaxf(pm, __shfl_xor(pm, off));
        float mnew = fmaxf(mrow[m][j], pm);
        float alpha = __expf(mrow[m][j] - mnew);
        mrow[m][j] = mnew;
        float rs = 0.f;
#pragma unroll
        for (int nf = 0; nf < 4; ++nf) {
          float pv = __expf(sfr[m][nf][j] - mnew);
          sfr[m][nf][j] = pv;
          rs += pv;
        }
#pragma unroll
        for (int off = 1; off < 16; off <<= 1) rs += __shfl_xor(rs, off);
        lrow[m][j] = lrow[m][j] * alpha + rs;
#pragma unroll
        for (int nd = 0; nd < 8; ++nd) o[m][nd][j] *= alpha;
      }
#pragma unroll
    for (int m = 0; m < 2; ++m)
#pragma unroll
      for (int nf = 0; nf < 4; ++nf)
#pragma unroll
        for (int j = 0; j < 4; ++j)
          Pl[wv][(m * 16 + (lane >> 4) * 4 + j) * 72 + nf * 16 + (lane & 15)] =
              f2bf(sfr[m][nf][j]);
    s16x8 pa[2][2];
#pragma unroll
    for (int m = 0; m < 2; ++m)
#pragma unroll
      for (int kf = 0; kf < 2; ++kf)
        pa[m][kf] = *(const s16x8*)&Pl[wv][(m * 16 + (lane & 15)) * 72 + kf * 32 + (lane >> 4) * 8];
    __builtin_amdgcn_s_setprio(1);
#pragma unroll
    for (int nd = 0; nd < 8; ++nd) {
      s16x8 vf[2];
      int drow = nd * 16 + (lane & 15);
      int key = ((drow >> 3) & 7) << 3;
#pragma unroll
      for (int kf = 0; kf < 2; ++kf)
        vf[kf] = *(const s16x8*)&Vl[drow * 72 + ((kf * 32 + (lane >> 4) * 8) ^ key)];
#pragma unroll
      for (int m = 0; m < 2; ++m)
#pragma unroll
        for (int kf = 0; kf < 2; ++kf) o[m][nd] = mfma16(pa[m][kf], vf[kf], o[m][nd]);
    }
    __builtin_amdgcn_s_setprio(0);
    __syncthreads();                 // all waves done reading Vl (and Kl[cb])
    if (more) storeV(vrb);           // write prefetched V tile
    __syncthreads();                 // drains next K gload before its use
  }
#pragma unroll
  for (int m = 0; m < 2; ++m)
#pragma unroll
    for (int nd = 0; nd < 8; ++nd)
#pragma unroll
      for (int j = 0; j < 4; ++j) {
        int r = q0 + m * 16 + (lane >> 4) * 4 + j;
        int c = h * HD + nd * 16 + (lane & 15);
        ob[(size_t)r * HID + c] = f2bf(o[m][nd][j] / lrow[m][j]);
      }
}

extern "C" void kernel_launch(void* const* d_in, const int* in_sizes, int n_in,
                              void* d_out, int out_size, void* d_ws, size_t ws_size,
                              hipStream_t stream) {
  const int* qw[7]; const int* qz[7]; const float* sc[7];
  for (int i = 0; i < 7; ++i) {
    qw[i] = (const int*)d_in[i * 3 + 0];
    qz[i] = (const int*)d_in[i * 3 + 1];
    sc[i] = (const float*)d_in[i * 3 + 2];
  }
  const float* hin  = (const float*)d_in[21];
  const float* ln1  = (const float*)d_in[22];
  const float* ln2  = (const float*)d_in[23];
  const float* sinp = (const float*)d_in[24];
  const float* cosp = (const float*)d_in[25];
  float* out = (float*)d_out;        // h2 lives here from o-proj onward

  char* ws = (char*)d_ws;
  const size_t MB = 1024 * 1024;
  // peak ws usage: 128 MB (proven-safe; round-8 layout verbatim)
  short* XB    = (short*)(ws);              // [0,16)  x1 then x2, bf16
  short* WA    = (short*)(ws + 16 * MB);    // [16,48)  weight buf A (32MB)
  short* WB    = (short*)(ws + 48 * MB);    // [48,80)  weight buf B (32MB)
  short* KB    = (short*)(ws + 80 * MB);    // [80,96)
  short* VB    = (short*)(ws + 96 * MB);    // [96,112)
  short* OB    = (short*)(ws + 112 * MB);   // [112,128)
  short* GATEB = (short*)(ws + 80 * MB);    // [80,123) aliases KB/VB/OB after attn
  short* QBd   = (short*)d_out;             // q bf16 in d_out[0:16MB) (dead until o-proj)

  dim3 blk(256);

  // L0: x1 = rms(h, ln1)  ||  dequant Wq -> WA  (merged launch)
  rmsdq_kernel<<<S_LEN + 4096, blk, 0, stream>>>(hin, ln1, XB, qw[0], qz[0], sc[0], WA, S_LEN);
  // L2: q = x1@Wq -> QBd  || dequant Wk -> WB
  paired_kernel<0><<<512 + 4096, blk, 0, stream>>>(XB, HID, WA, HID, QBd, HID, nullptr, HID,
                                                   32, 16, qw[1], qz[1], sc[1], WB, HID, 0, 64, HID);
  // L3: k -> KB || dequant Wv -> WA
  paired_kernel<0><<<512 + 4096, blk, 0, stream>>>(XB, HID, WB, HID, KB, HID, nullptr, HID,
                                                   32, 16, qw[2], qz[2], sc[2], WA, HID, 0, 64, HID);
  // L4: v -> VB || dequant Wo -> WB
  paired_kernel<0><<<512 + 4096, blk, 0, stream>>>(XB, HID, WA, HID, VB, HID, nullptr, HID,
                                                   32, 16, qw[3], qz[3], sc[3], WB, HID, 0, 64, HID);
  // L5/L6: rope + attention (balanced 1D grid)
  rope_kernel<<<S_LEN, blk, 0, stream>>>(QBd, KB, sinp, cosp);
  attn_kernel<<<512, blk, 0, stream>>>(QBd, KB, VB, OB);
  // L7: h2 = h + o@Wo -> d_out || dequant gate_c0 -> WA
  paired_kernel<1><<<512 + 4096, blk, 0, stream>>>(OB, HID, WB, HID, out, HID, hin, HID,
                                                   32, 16, qw[4], qz[4], sc[4], WA, INTER, 0, 64, HID);
  // L8: x2 = rms(h2, ln2)
  rmsnorm_kernel<<<S_LEN, blk, 0, stream>>>(out, ln2, XB);

  // MLP: per chunk c: gate_c (OMODE0) then up_c (OMODE3: y=silu(gate)*up in place),
  // each paired with the next dequant. Buffers alternate WA/WB strictly.
  // L9:  gate_c0 (WA) || dq up_c0 -> WB
  paired_kernel<0><<<512 + 4096, blk, 0, stream>>>(XB, HID, WA, HID, GATEB + 0, INTER, nullptr, HID,
                                                   32, 16, qw[5], qz[5], sc[5], WB, INTER, 0, 64, HID);
  // L10: up_c0 (WB) || dq gate_c1 -> WA
  paired_kernel<3><<<512 + 4096, blk, 0, stream>>>(XB, HID, WB, HID, GATEB + 0, INTER, nullptr, HID,
                                                   32, 16, qw[4], qz[4], sc[4], WA, INTER, 4096, 64, HID);
  // L11: gate_c1 (WA) || dq up_c1 -> WB
  paired_kernel<0><<<512 + 4096, blk, 0, stream>>>(XB, HID, WA, HID, GATEB + 4096, INTER, nullptr, HID,
                                                   32, 16, qw[5], qz[5], sc[5], WB, INTER, 4096, 64, HID);
  // L12: up_c1 (WB) || dq gate_c2 -> WA (2816 cols -> 44x64 blocks)
  paired_kernel<3><<<512 + 2816, blk, 0, stream>>>(XB, HID, WB, HID, GATEB + 4096, INTER, nullptr, HID,
                                                   32, 16, qw[4], qz[4], sc[4], WA, INTER, 8192, 44, HID);
  // L13: gate_c2 (WA, gnx=22) || dq up_c2 -> WB
  paired_kernel<0><<<352 + 2816, blk, 0, stream>>>(XB, HID, WA, HID, GATEB + 8192, INTER, nullptr, HID,
                                                   22, 16, qw[5], qz[5], sc[5], WB, INTER, 8192, 44, HID);
  // L14: up_c2 (WB, gnx=22) || dq down_c0 -> WA
  paired_kernel<3><<<352 + 4096, blk, 0, stream>>>(XB, HID, WB, HID, GATEB + 8192, INTER, nullptr, HID,
                                                   22, 16, qw[6], qz[6], sc[6], WA, HID, 0, 64, 4096);
  // L15: down_c0: out += y[:,0:4096]@Wd0 (WA) || dq down_c1 -> WB
  paired_kernel<2><<<512 + 4096, blk, 0, stream>>>(GATEB + 0, INTER, WA, 4096, out, HID, nullptr, 4096,
                                                   32, 16,
                                                   qw[6] + (size_t)(4096 >> 3) * HID,
                                                   qz[6] + (size_t)(4096 >> 7) * (HID / 8),
                                                   sc[6] + (size_t)(4096 >> 7) * HID,
                                                   WB, HID, 0, 64, 4096);
  // L16: down_c1 (WB) || dq down_c2 -> WA (2816 k -> 64x44 blocks)
  paired_kernel<2><<<512 + 2816, blk, 0, stream>>>(GATEB + 4096, INTER, WB, 4096, out, HID, nullptr, 4096,
                                                   32, 16,
                                                   qw[6] + (size_t)(8192 >> 3) * HID,
                                                   qz[6] + (size_t)(8192 >> 7) * (HID / 8),
                                                   sc[6] + (size_t)(8192 >> 7) * HID,
                                                   WA, HID, 0, 64, 2816);
  // L17: down_c2 (WA, Kext=2816), pure gemm
  paired_kernel<2><<<512, blk, 0, stream>>>(GATEB + 8192, INTER, WA, 2816, out, HID, nullptr, 2816,
                                            32, 16, nullptr, nullptr, nullptr, nullptr, HID, 0, 1, HID);
}